// Round 5
// baseline (820.721 us; speedup 1.0000x reference)
//
#include <hip/hip_runtime.h>
#include <hip/hip_bf16.h>

#define N_GRAPHS 128
#define BN_EPS 1e-5f
#define CHUNK 8192
#define NBU 512            // padded bucket count (actual NB = ceil(N/128) = 391)
#define CAP 8192           // per-bucket edge capacity (mean 4096, sd ~64)

typedef short bf16x8 __attribute__((ext_vector_type(8)));
typedef short s16x4 __attribute__((ext_vector_type(4)));
typedef float f32x4 __attribute__((ext_vector_type(4)));

__device__ __forceinline__ unsigned short f2b(float f) {   // f32 -> bf16 RNE
    unsigned int u = __builtin_bit_cast(unsigned int, f);
    u += 0x7FFFu + ((u >> 16) & 1u);
    return (unsigned short)(u >> 16);
}
__device__ __forceinline__ float b2f_lo(unsigned int p) {
    return __builtin_bit_cast(float, p << 16);
}
__device__ __forceinline__ float b2f_hi(unsigned int p) {
    return __builtin_bit_cast(float, p & 0xFFFF0000u);
}

// ---------------- K1: per-chunk bucket binning (no global scatter atomics) ----------------
__global__ __launch_bounds__(512) void bin_chunks(const int* __restrict__ src,
                                                  const int* __restrict__ dst,
                                                  unsigned int* __restrict__ bpairs,
                                                  int* __restrict__ cnts,
                                                  int* __restrict__ cbase,
                                                  int* __restrict__ btot, int E) {
    __shared__ int lhist[NBU], lscan[NBU], lfill[NBU];
    int tid = threadIdx.x;
    int c0 = blockIdx.x * CHUNK;
    int ecnt = min(CHUNK, E - c0);
    lhist[tid] = 0;
    __syncthreads();
    for (int i = tid; i < ecnt; i += 512)
        atomicAdd(&lhist[((unsigned)dst[c0 + i]) >> 7], 1);
    __syncthreads();
    int orig = lhist[tid];
    atomicAdd(&btot[tid], orig);          // global column-sum for bucket_scan
    lscan[tid] = orig;
    __syncthreads();
    for (int off = 1; off < NBU; off <<= 1) {
        int t = (tid >= off) ? lscan[tid - off] : 0;
        __syncthreads();
        lscan[tid] += t;
        __syncthreads();
    }
    int excl = lscan[tid] - orig;
    cnts[blockIdx.x * NBU + tid] = orig;
    cbase[blockIdx.x * NBU + tid] = excl;
    lfill[tid] = 0;
    __syncthreads();
    lscan[tid] = excl;
    __syncthreads();
    for (int i = tid; i < ecnt; i += 512) {
        int d = dst[c0 + i], s = src[c0 + i];
        int b = ((unsigned)d) >> 7;
        int pos = lscan[b] + atomicAdd(&lfill[b], 1);
        bpairs[c0 + pos] = ((unsigned)(d & 127) << 25) | (unsigned)s;
    }
}

// ---------------- K2: bucket bases (scan of btot) ----------------
__global__ __launch_bounds__(512) void bucket_scan(const int* __restrict__ btot,
                                                   int* __restrict__ bucket_base) {
    __shared__ int s[NBU];
    int b = threadIdx.x;
    int tot = btot[b];
    s[b] = tot;
    __syncthreads();
    for (int off = 1; off < NBU; off <<= 1) {
        int t = (b >= off) ? s[b - off] : 0;
        __syncthreads();
        s[b] += t;
        __syncthreads();
    }
    bucket_base[b] = s[b] - tot;   // exclusive
}

// ---------------- K3: per-bucket CSR finalize (coalesced writes) ----------------
__global__ __launch_bounds__(256) void bucket_csr(const unsigned int* __restrict__ bpairs,
                                                  const int* __restrict__ cnts,
                                                  const int* __restrict__ cbase,
                                                  const int* __restrict__ bucket_base,
                                                  int* __restrict__ rowp,
                                                  int* __restrict__ degarr,
                                                  float* __restrict__ dinv,
                                                  int* __restrict__ csr,
                                                  int nchunks, int N) {
    __shared__ unsigned int lpr[CAP];
    __shared__ int lcsr[CAP];
    __shared__ int ccnt[256], cofs[256], cb[256];
    __shared__ int lhist[128], lofs[128], lfill[128];
    int tid = threadIdx.x;
    int b = blockIdx.x;
    int bb = bucket_base[b];
    int total = bucket_base[b + 1] - bb;
    if (total > CAP) total = CAP;

    ccnt[tid] = (tid < nchunks) ? cnts[tid * NBU + b] : 0;
    cb[tid]   = (tid < nchunks) ? cbase[tid * NBU + b] : 0;
    cofs[tid] = ccnt[tid];
    __syncthreads();
    int orig = cofs[tid];
    for (int off = 1; off < 256; off <<= 1) {
        int t = (tid >= off) ? cofs[tid - off] : 0;
        __syncthreads();
        cofs[tid] += t;
        __syncthreads();
    }
    int o = cofs[tid] - orig;
    if (tid < nchunks) {
        int len = ccnt[tid];
        const unsigned int* p = bpairs + (size_t)tid * CHUNK + cb[tid];
        for (int i = 0; i < len; ++i) {
            int q = o + i;
            if (q < CAP) lpr[q] = p[i];
        }
    }
    if (tid < 128) { lhist[tid] = 0; lfill[tid] = 0; }
    __syncthreads();
    for (int i = tid; i < total; i += 256)
        atomicAdd(&lhist[lpr[i] >> 25], 1);
    __syncthreads();
    if (tid < 128) lofs[tid] = lhist[tid];
    __syncthreads();
    for (int off = 1; off < 128; off <<= 1) {
        int t = 0;
        if (tid < 128 && tid >= off) t = lofs[tid - off];
        __syncthreads();
        if (tid < 128) lofs[tid] += t;
        __syncthreads();
    }
    if (tid < 128) {
        int v = b * 128 + tid;
        if (v < N) {
            int dg = lhist[tid];
            degarr[v] = dg;
            rowp[v] = bb + lofs[tid] - dg;
            dinv[v] = rsqrtf((float)(dg + 1));
        }
    }
    __syncthreads();
    for (int i = tid; i < total; i += 256) {
        unsigned int pr = lpr[i];
        int dl = pr >> 25;
        int pos = lofs[dl] - lhist[dl] + atomicAdd(&lfill[dl], 1);
        if (pos < CAP) lcsr[pos] = (int)(pr & 0x1FFFFFFu);
    }
    __syncthreads();
    for (int i = tid; i < total; i += 256) csr[bb + i] = lcsr[i];
}

// ---------------- MFMA GEMM: hW(4-slab bf16) = BN(A) @ W ----------------
// AF32=1: A is f32 row-major x, no BN fold. AF32=0: A is raw z32 bf16 [N][128];
// BN folded: W rows scaled by sc at staging, wb[c]=sh@W added in epilogue.
// Output layout: 4 slabs of [N][32] bf16 (slab q = cols q*32..q*32+31).
template <int AF32>
__global__ __launch_bounds__(256) void gemm_mfma(const void* __restrict__ Avoid,
                                                 const float* __restrict__ W,
                                                 const float* __restrict__ ssPrev,
                                                 const float* __restrict__ wb,
                                                 unsigned short* __restrict__ Cb, int N) {
    __shared__ unsigned short sWt[128 * 128];
    int tid = threadIdx.x;
    for (int i = tid; i < 128 * 128; i += 256) {
        int k = i >> 7, c = i & 127;
        float w = W[i];
        if (!AF32) w *= ssPrev[k];
        int kk = k & 31, k0 = k >> 5;
        int hi = (kk >> 2) & 3;
        int e = (kk & 3) + 4 * (kk >> 4);
        int idx = c * 128 + k0 * 32 + hi * 8 + e;
        sWt[idx ^ ((c & 7) << 3)] = f2b(w);
    }
    __syncthreads();

    int wave = tid >> 6, lane = tid & 63;
    int lo4 = lane & 15, hi = lane >> 4;
    int rowBase = blockIdx.x * 256 + wave * 64;

    f32x4 acc[8][4];
#pragma unroll
    for (int ct = 0; ct < 8; ++ct)
#pragma unroll
        for (int rt = 0; rt < 4; ++rt) acc[ct][rt] = (f32x4){0.f, 0.f, 0.f, 0.f};

    const float* Af = (const float*)Avoid;
    const unsigned short* Ab = (const unsigned short*)Avoid;

    for (int k0 = 0; k0 < 128; k0 += 32) {
        bf16x8 bfrag[4];
#pragma unroll
        for (int rt = 0; rt < 4; ++rt) {
            int r = rowBase + rt * 16 + lo4;
            if (r >= N) r = N - 1;
            if (AF32) {
                float4 f0 = *(const float4*)(Af + (size_t)r * 128 + k0 + 4 * hi);
                float4 f1 = *(const float4*)(Af + (size_t)r * 128 + k0 + 16 + 4 * hi);
                bf16x8 f;
                f[0] = (short)f2b(f0.x); f[1] = (short)f2b(f0.y);
                f[2] = (short)f2b(f0.z); f[3] = (short)f2b(f0.w);
                f[4] = (short)f2b(f1.x); f[5] = (short)f2b(f1.y);
                f[6] = (short)f2b(f1.z); f[7] = (short)f2b(f1.w);
                bfrag[rt] = f;
            } else {
                s16x4 a0 = *(const s16x4*)(Ab + (size_t)r * 128 + k0 + 4 * hi);
                s16x4 a1 = *(const s16x4*)(Ab + (size_t)r * 128 + k0 + 16 + 4 * hi);
                bf16x8 f;
                f[0] = a0[0]; f[1] = a0[1]; f[2] = a0[2]; f[3] = a0[3];
                f[4] = a1[0]; f[5] = a1[1]; f[6] = a1[2]; f[7] = a1[3];
                bfrag[rt] = f;
            }
        }
        int kq = k0 >> 5;
#pragma unroll
        for (int ct = 0; ct < 8; ++ct) {
            int c = ct * 16 + lo4;
            int idx = (c * 128 + kq * 32 + hi * 8) ^ ((c & 7) << 3);
            bf16x8 af = *(const bf16x8*)(sWt + idx);
#pragma unroll
            for (int rt = 0; rt < 4; ++rt)
                acc[ct][rt] = __builtin_amdgcn_mfma_f32_16x16x32_bf16(af, bfrag[rt], acc[ct][rt], 0, 0, 0);
        }
    }

#pragma unroll
    for (int rt = 0; rt < 4; ++rt) {
        int r = rowBase + rt * 16 + lo4;
        if (r < N) {
#pragma unroll
            for (int ct = 0; ct < 8; ++ct) {
                int c0 = ct * 16 + hi * 4;
                float4 wbv = make_float4(0.f, 0.f, 0.f, 0.f);
                if (!AF32) wbv = *(const float4*)(wb + c0);
                ushort4 s;
                s.x = f2b(acc[ct][rt][0] + wbv.x);
                s.y = f2b(acc[ct][rt][1] + wbv.y);
                s.z = f2b(acc[ct][rt][2] + wbv.z);
                s.w = f2b(acc[ct][rt][3] + wbv.w);
                int q = c0 >> 5;
                *(ushort4*)(Cb + (size_t)q * N * 32 + (size_t)r * 32 + (c0 & 31)) = s;
            }
        }
    }
}

// ---------------- aggregation + bias + relu: slab-major, one wave per (node, slab) ----------------
// hW in 4 slabs of [N][16] u32 (3.2 MB each -> L2-resident per XCD).
// wave: lane = e*16+dd; 4 edges in flight (e), 16 u32 cols (dd); shfl_xor reduce over e.
__global__ __launch_bounds__(256) void agg_relu_slab(const unsigned int* __restrict__ hW32,
                                                     const int* __restrict__ rowp,
                                                     const int* __restrict__ cnt,
                                                     const int* __restrict__ csr,
                                                     const float* __restrict__ dinv,
                                                     const float* __restrict__ bias,
                                                     unsigned int* __restrict__ z32,
                                                     int ngroups, int N) {
    int q = blockIdx.x / ngroups;            // slab-major dispatch
    int group = blockIdx.x % ngroups;
    int wave = threadIdx.x >> 6, lane = threadIdx.x & 63;
    int v = group * 4 + wave;
    if (v >= N) return;
    int dd = lane & 15, e = lane >> 4;
    const unsigned int* hWq = hW32 + (size_t)q * N * 16;

    int beg = rowp[v];
    int num = cnt[v];
    float s0 = 0.f, s1 = 0.f;
    int iters = (num + 3) >> 2;
    for (int i = 0; i < iters; ++i) {
        int idx = 4 * i + e;
        bool ok = idx < num;
        int u = ok ? csr[beg + idx] : v;
        float w = ok ? dinv[u] : 0.f;
        unsigned int p = hWq[(size_t)u * 16 + dd];
        s0 += w * b2f_lo(p);
        s1 += w * b2f_hi(p);
    }
    s0 += __shfl_xor(s0, 16, 64);
    s0 += __shfl_xor(s0, 32, 64);
    s1 += __shfl_xor(s1, 16, 64);
    s1 += __shfl_xor(s1, 32, 64);
    if (e == 0) {
        float dv = dinv[v];
        unsigned int pv = hWq[(size_t)v * 16 + dd];
        float r0 = dv * s0 + dv * dv * b2f_lo(pv) + bias[q * 32 + 2 * dd];
        float r1 = dv * s1 + dv * dv * b2f_hi(pv) + bias[q * 32 + 2 * dd + 1];
        unsigned int po = (unsigned int)f2b(fmaxf(r0, 0.f)) |
                          ((unsigned int)f2b(fmaxf(r1, 0.f)) << 16);
        z32[(size_t)v * 64 + q * 16 + dd] = po;   // row-major [N][128] bf16
    }
}

// ---------------- BN statistics (bf16 input, row-major) ----------------
__global__ __launch_bounds__(256) void bn_stats_b16(const unsigned int* __restrict__ z32,
                                                    float* __restrict__ stats, int N) {
    int lane = threadIdx.x & 63, sub = threadIdx.x >> 6;
    float s0 = 0.f, s1 = 0.f, q0 = 0.f, q1 = 0.f;
    for (int v = blockIdx.x * 4 + sub; v < N; v += gridDim.x * 4) {
        unsigned int p = z32[(size_t)v * 64 + lane];
        float a = b2f_lo(p), c = b2f_hi(p);
        s0 += a; q0 = fmaf(a, a, q0);
        s1 += c; q1 = fmaf(c, c, q1);
    }
    __shared__ float ls[256][4];
    ls[threadIdx.x][0] = s0; ls[threadIdx.x][1] = s1;
    ls[threadIdx.x][2] = q0; ls[threadIdx.x][3] = q1;
    __syncthreads();
    if (sub == 0) {
        for (int k = 1; k < 4; ++k) {
            s0 += ls[lane + 64 * k][0]; s1 += ls[lane + 64 * k][1];
            q0 += ls[lane + 64 * k][2]; q1 += ls[lane + 64 * k][3];
        }
        atomicAdd(&stats[2 * lane], s0);
        atomicAdd(&stats[2 * lane + 1], s1);
        atomicAdd(&stats[128 + 2 * lane], q0);
        atomicAdd(&stats[129 + 2 * lane], q1);
    }
}

// ---------------- BN finalize + wb = sh @ Wnext for the next GEMM ----------------
__global__ void bn_finalize_wb(const float* __restrict__ stats, const float* __restrict__ g,
                               const float* __restrict__ be, float* __restrict__ ss,
                               const float* __restrict__ Wnext, float* __restrict__ wb,
                               float invN) {
    __shared__ float shv[128];
    int d = threadIdx.x;  // 128 threads
    float mu = stats[d] * invN;
    float var = stats[128 + d] * invN - mu * mu;
    float sc = g[d] * rsqrtf(var + BN_EPS);
    float sh = be[d] - mu * sc;
    ss[d] = sc;
    ss[128 + d] = sh;
    shv[d] = sh;
    __syncthreads();
    if (Wnext) {
        float acc = 0.f;
#pragma unroll 4
        for (int k = 0; k < 128; ++k) acc = fmaf(shv[k], Wnext[k * 128 + d], acc);
        wb[d] = acc;
    }
}

// ---------------- apply BN + pooled segment sum (read-only on z32) ----------------
__global__ __launch_bounds__(64) void apply_pool_b16(const unsigned int* __restrict__ z32,
                                                     const float* __restrict__ ss,
                                                     const int* __restrict__ batch,
                                                     float* __restrict__ out,
                                                     int layer, int N) {
    __shared__ int gb[32];
    int lane = threadIdx.x;
    int v0 = blockIdx.x * 32;
    int vend = min(v0 + 32, N);
    int cntv = vend - v0;
    if (lane < cntv) gb[lane] = batch[v0 + lane];
    __syncthreads();
    float sc0 = ss[2 * lane], sc1 = ss[2 * lane + 1];
    float sh0 = ss[128 + 2 * lane], sh1 = ss[129 + 2 * lane];
    float a0 = 0.f, a1 = 0.f;
    int cur = gb[0];
    for (int j = 0; j < cntv; ++j) {
        unsigned int p = z32[(size_t)(v0 + j) * 64 + lane];
        float x0 = fmaf(b2f_lo(p), sc0, sh0);
        float x1 = fmaf(b2f_hi(p), sc1, sh1);
        int g = gb[j];
        if (g != cur) {
            atomicAdd(&out[(size_t)cur * 384 + layer * 128 + 2 * lane], a0);
            atomicAdd(&out[(size_t)cur * 384 + layer * 128 + 2 * lane + 1], a1);
            a0 = a1 = 0.f;
            cur = g;
        }
        a0 += x0; a1 += x1;
    }
    atomicAdd(&out[(size_t)cur * 384 + layer * 128 + 2 * lane], a0);
    atomicAdd(&out[(size_t)cur * 384 + layer * 128 + 2 * lane + 1], a1);
}

// ---------------- launch ----------------
extern "C" void kernel_launch(void* const* d_in, const int* in_sizes, int n_in,
                              void* d_out, int out_size, void* d_ws, size_t ws_size,
                              hipStream_t stream) {
    const float* x    = (const float*)d_in[0];
    const int* eidx   = (const int*)d_in[1];
    const int* batch  = (const int*)d_in[2];

    const int N = in_sizes[2];          // 50000
    const int E = in_sizes[1] / 2;      // 1600000
    const int* src = eidx;
    const int* dst = eidx + E;

    const int nchunks = (E + CHUNK - 1) / CHUNK;   // 196
    const int NB = (N + 127) / 128;                // 391

    size_t off = 0;
    auto alloc = [&](size_t bytes) {
        void* p = (char*)d_ws + off;
        off += (bytes + 255) & ~(size_t)255;
        return p;
    };
    unsigned short* hWb = (unsigned short*)alloc((size_t)N * 128 * 2);  // 4-slab bf16 h@W
    unsigned int* z32   = (unsigned int*)alloc((size_t)N * 64 * 4);     // bf16 post-agg row-major
    unsigned int* bpairs= (unsigned int*)alloc((size_t)nchunks * CHUNK * 4);
    int*   csr   = (int*)alloc((size_t)E * 4);
    int*   cnts  = (int*)alloc((size_t)nchunks * NBU * 4);
    int*   cbase = (int*)alloc((size_t)nchunks * NBU * 4);
    int*   bbase = (int*)alloc((size_t)(NBU + 1) * 4);
    int*   btot  = (int*)alloc((size_t)NBU * 4);
    int*   degar = (int*)alloc((size_t)N * 4);
    int*   rowp  = (int*)alloc((size_t)N * 4);
    float* dinv  = (float*)alloc((size_t)N * 4);
    float* stats = (float*)alloc(3 * 256 * 4);
    float* ss    = (float*)alloc(3 * 256 * 4);
    float* wbuf  = (float*)alloc(2 * 128 * 4);

    float* out = (float*)d_out;

    hipMemsetAsync(stats, 0, 3 * 256 * 4, stream);
    hipMemsetAsync(btot, 0, (size_t)NBU * 4, stream);
    hipMemsetAsync(out, 0, (size_t)N_GRAPHS * 384 * 4, stream);

    bin_chunks<<<nchunks, 512, 0, stream>>>(src, dst, bpairs, cnts, cbase, btot, E);
    bucket_scan<<<1, 512, 0, stream>>>(btot, bbase);
    bucket_csr<<<NB, 256, 0, stream>>>(bpairs, cnts, cbase, bbase, rowp, degar, dinv, csr,
                                       nchunks, N);

    const int gemm_blocks = (N + 255) / 256;   // 196
    const int ngroups     = (N + 3) / 4;       // 12500
    const int agg_blocks  = 4 * ngroups;       // 50000 (slab-major)
    const int pool_blocks = (N + 31) / 32;     // 1563

    for (int l = 0; l < 3; ++l) {
        const float* W  = (const float*)d_in[3 + 4 * l];
        const float* b  = (const float*)d_in[4 + 4 * l];
        const float* g  = (const float*)d_in[5 + 4 * l];
        const float* be = (const float*)d_in[6 + 4 * l];

        if (l == 0)
            gemm_mfma<1><<<gemm_blocks, 256, 0, stream>>>((const void*)x, W, nullptr, nullptr,
                                                          hWb, N);
        else
            gemm_mfma<0><<<gemm_blocks, 256, 0, stream>>>((const void*)z32, W,
                                                          ss + (l - 1) * 256, wbuf + (l - 1) * 128,
                                                          hWb, N);

        agg_relu_slab<<<agg_blocks, 256, 0, stream>>>((const unsigned int*)hWb, rowp, degar, csr,
                                                      dinv, b, z32, ngroups, N);
        bn_stats_b16<<<256, 256, 0, stream>>>(z32, stats + l * 256, N);
        bn_finalize_wb<<<1, 128, 0, stream>>>(stats + l * 256, g, be, ss + l * 256,
                                              (l < 2) ? (const float*)d_in[3 + 4 * (l + 1)]
                                                      : (const float*)nullptr,
                                              wbuf + l * 128, 1.0f / N);
        apply_pool_b16<<<pool_blocks, 64, 0, stream>>>(z32, ss + l * 256, batch, out, l, N);
    }
}

// Round 6
// 491.235 us; speedup vs baseline: 1.6707x; 1.6707x over previous
//
#include <hip/hip_runtime.h>
#include <hip/hip_bf16.h>

#define N_GRAPHS 128
#define BN_EPS 1e-5f
#define CHUNK 8192
#define NBU 512            // padded bucket count (actual NB = ceil(N/128) = 391)
#define CAP 8192           // per-bucket edge capacity (mean 4096, sd ~64)

typedef short bf16x8 __attribute__((ext_vector_type(8)));
typedef short s16x4 __attribute__((ext_vector_type(4)));
typedef float f32x4 __attribute__((ext_vector_type(4)));

__device__ __forceinline__ unsigned short f2b(float f) {   // f32 -> bf16 RNE
    unsigned int u = __builtin_bit_cast(unsigned int, f);
    u += 0x7FFFu + ((u >> 16) & 1u);
    return (unsigned short)(u >> 16);
}
__device__ __forceinline__ float b2f_lo(unsigned int p) {
    return __builtin_bit_cast(float, p << 16);
}
__device__ __forceinline__ float b2f_hi(unsigned int p) {
    return __builtin_bit_cast(float, p & 0xFFFF0000u);
}

// ---------------- K1: per-chunk bucket binning (no global scatter atomics) ----------------
__global__ __launch_bounds__(512) void bin_chunks(const int* __restrict__ src,
                                                  const int* __restrict__ dst,
                                                  unsigned int* __restrict__ bpairs,
                                                  int* __restrict__ cnts,
                                                  int* __restrict__ cbase,
                                                  int* __restrict__ btot, int E) {
    __shared__ int lhist[NBU], lscan[NBU], lfill[NBU];
    int tid = threadIdx.x;
    int c0 = blockIdx.x * CHUNK;
    int ecnt = min(CHUNK, E - c0);
    lhist[tid] = 0;
    __syncthreads();
    for (int i = tid; i < ecnt; i += 512)
        atomicAdd(&lhist[((unsigned)dst[c0 + i]) >> 7], 1);
    __syncthreads();
    int orig = lhist[tid];
    atomicAdd(&btot[tid], orig);
    lscan[tid] = orig;
    __syncthreads();
    for (int off = 1; off < NBU; off <<= 1) {
        int t = (tid >= off) ? lscan[tid - off] : 0;
        __syncthreads();
        lscan[tid] += t;
        __syncthreads();
    }
    int excl = lscan[tid] - orig;
    cnts[blockIdx.x * NBU + tid] = orig;
    cbase[blockIdx.x * NBU + tid] = excl;
    lfill[tid] = 0;
    __syncthreads();
    lscan[tid] = excl;
    __syncthreads();
    for (int i = tid; i < ecnt; i += 512) {
        int d = dst[c0 + i], s = src[c0 + i];
        int b = ((unsigned)d) >> 7;
        int pos = lscan[b] + atomicAdd(&lfill[b], 1);
        bpairs[c0 + pos] = ((unsigned)(d & 127) << 25) | (unsigned)s;
    }
}

// ---------------- K2: bucket bases (scan of btot) ----------------
__global__ __launch_bounds__(512) void bucket_scan(const int* __restrict__ btot,
                                                   int* __restrict__ bucket_base) {
    __shared__ int s[NBU];
    int b = threadIdx.x;
    int tot = btot[b];
    s[b] = tot;
    __syncthreads();
    for (int off = 1; off < NBU; off <<= 1) {
        int t = (b >= off) ? s[b - off] : 0;
        __syncthreads();
        s[b] += t;
        __syncthreads();
    }
    bucket_base[b] = s[b] - tot;   // exclusive
}

// ---------------- K3: per-bucket CSR finalize (coalesced writes) ----------------
__global__ __launch_bounds__(256) void bucket_csr(const unsigned int* __restrict__ bpairs,
                                                  const int* __restrict__ cnts,
                                                  const int* __restrict__ cbase,
                                                  const int* __restrict__ bucket_base,
                                                  int* __restrict__ rowp,
                                                  int* __restrict__ degarr,
                                                  float* __restrict__ dinv,
                                                  int* __restrict__ csr,
                                                  int nchunks, int N) {
    __shared__ unsigned int lpr[CAP];
    __shared__ int lcsr[CAP];
    __shared__ int ccnt[256], cofs[256], cb[256];
    __shared__ int lhist[128], lofs[128], lfill[128];
    int tid = threadIdx.x;
    int b = blockIdx.x;
    int bb = bucket_base[b];
    int total = bucket_base[b + 1] - bb;
    if (total > CAP) total = CAP;

    ccnt[tid] = (tid < nchunks) ? cnts[tid * NBU + b] : 0;
    cb[tid]   = (tid < nchunks) ? cbase[tid * NBU + b] : 0;
    cofs[tid] = ccnt[tid];
    __syncthreads();
    int orig = cofs[tid];
    for (int off = 1; off < 256; off <<= 1) {
        int t = (tid >= off) ? cofs[tid - off] : 0;
        __syncthreads();
        cofs[tid] += t;
        __syncthreads();
    }
    int o = cofs[tid] - orig;
    if (tid < nchunks) {
        int len = ccnt[tid];
        const unsigned int* p = bpairs + (size_t)tid * CHUNK + cb[tid];
        for (int i = 0; i < len; ++i) {
            int q = o + i;
            if (q < CAP) lpr[q] = p[i];
        }
    }
    if (tid < 128) { lhist[tid] = 0; lfill[tid] = 0; }
    __syncthreads();
    for (int i = tid; i < total; i += 256)
        atomicAdd(&lhist[lpr[i] >> 25], 1);
    __syncthreads();
    if (tid < 128) lofs[tid] = lhist[tid];
    __syncthreads();
    for (int off = 1; off < 128; off <<= 1) {
        int t = 0;
        if (tid < 128 && tid >= off) t = lofs[tid - off];
        __syncthreads();
        if (tid < 128) lofs[tid] += t;
        __syncthreads();
    }
    if (tid < 128) {
        int v = b * 128 + tid;
        if (v < N) {
            int dg = lhist[tid];
            degarr[v] = dg;
            rowp[v] = bb + lofs[tid] - dg;
            dinv[v] = rsqrtf((float)(dg + 1));
        }
    }
    __syncthreads();
    for (int i = tid; i < total; i += 256) {
        unsigned int pr = lpr[i];
        int dl = pr >> 25;
        int pos = lofs[dl] - lhist[dl] + atomicAdd(&lfill[dl], 1);
        if (pos < CAP) lcsr[pos] = (int)(pr & 0x1FFFFFFu);
    }
    __syncthreads();
    for (int i = tid; i < total; i += 256) csr[bb + i] = lcsr[i];
}

// ---------------- W prep: bf16 convert + BN row-scale + MFMA swizzle (to global) --------
__global__ __launch_bounds__(256) void prep_w(const float* __restrict__ W,
                                              const float* __restrict__ sc,
                                              unsigned short* __restrict__ Wp) {
    int i = blockIdx.x * 256 + threadIdx.x;   // 64 blocks x 256
    int k = i >> 7, c = i & 127;
    float w = W[i];
    if (sc) w *= sc[k];
    int kk = k & 31, k0 = k >> 5;
    int hi = (kk >> 2) & 3;
    int e = (kk & 3) + 4 * (kk >> 4);
    int idx = c * 128 + k0 * 32 + hi * 8 + e;
    Wp[idx ^ ((c & 7) << 3)] = f2b(w);
}

// ---------------- MFMA GEMM: hW'[N,128](bf16) = dinv * (BN(A) @ W) ----------------
// Wp is prepped (bf16, swizzled, BN-scaled). wb = sh@W added in epilogue (l>=1).
// Row-scaled by dinv[r] so agg needs no per-edge dinv load.
template <int AF32>
__global__ __launch_bounds__(256) void gemm_mfma(const void* __restrict__ Avoid,
                                                 const unsigned short* __restrict__ Wp,
                                                 const float* __restrict__ wb,
                                                 const float* __restrict__ dinv,
                                                 unsigned short* __restrict__ Cb, int N) {
    __shared__ unsigned short sWt[128 * 128];
    int tid = threadIdx.x;
    // straight 32 KB copy, 128 B per thread
    {
        const uint4* src = (const uint4*)Wp;
        uint4* dst = (uint4*)sWt;
#pragma unroll
        for (int j = 0; j < 8; ++j) dst[tid + 256 * j] = src[tid + 256 * j];
    }
    __syncthreads();

    int wave = tid >> 6, lane = tid & 63;
    int lo4 = lane & 15, hi = lane >> 4;
    int rowBase = blockIdx.x * 128 + wave * 32;

    f32x4 acc[8][2];
#pragma unroll
    for (int ct = 0; ct < 8; ++ct)
#pragma unroll
        for (int rt = 0; rt < 2; ++rt) acc[ct][rt] = (f32x4){0.f, 0.f, 0.f, 0.f};

    const float* Af = (const float*)Avoid;
    const unsigned short* Ab = (const unsigned short*)Avoid;

    for (int k0 = 0; k0 < 128; k0 += 32) {
        bf16x8 bfrag[2];
#pragma unroll
        for (int rt = 0; rt < 2; ++rt) {
            int r = rowBase + rt * 16 + lo4;
            if (r >= N) r = N - 1;
            if (AF32) {
                float4 f0 = *(const float4*)(Af + (size_t)r * 128 + k0 + 4 * hi);
                float4 f1 = *(const float4*)(Af + (size_t)r * 128 + k0 + 16 + 4 * hi);
                bf16x8 f;
                f[0] = (short)f2b(f0.x); f[1] = (short)f2b(f0.y);
                f[2] = (short)f2b(f0.z); f[3] = (short)f2b(f0.w);
                f[4] = (short)f2b(f1.x); f[5] = (short)f2b(f1.y);
                f[6] = (short)f2b(f1.z); f[7] = (short)f2b(f1.w);
                bfrag[rt] = f;
            } else {
                s16x4 a0 = *(const s16x4*)(Ab + (size_t)r * 128 + k0 + 4 * hi);
                s16x4 a1 = *(const s16x4*)(Ab + (size_t)r * 128 + k0 + 16 + 4 * hi);
                bf16x8 f;
                f[0] = a0[0]; f[1] = a0[1]; f[2] = a0[2]; f[3] = a0[3];
                f[4] = a1[0]; f[5] = a1[1]; f[6] = a1[2]; f[7] = a1[3];
                bfrag[rt] = f;
            }
        }
        int kq = k0 >> 5;
#pragma unroll
        for (int ct = 0; ct < 8; ++ct) {
            int c = ct * 16 + lo4;
            int idx = (c * 128 + kq * 32 + hi * 8) ^ ((c & 7) << 3);
            bf16x8 af = *(const bf16x8*)(sWt + idx);
#pragma unroll
            for (int rt = 0; rt < 2; ++rt)
                acc[ct][rt] = __builtin_amdgcn_mfma_f32_16x16x32_bf16(af, bfrag[rt], acc[ct][rt], 0, 0, 0);
        }
    }

#pragma unroll
    for (int rt = 0; rt < 2; ++rt) {
        int r = rowBase + rt * 16 + lo4;
        if (r < N) {
            float dv = dinv[r];
#pragma unroll
            for (int ct = 0; ct < 8; ++ct) {
                int c0 = ct * 16 + hi * 4;
                float4 wbv = make_float4(0.f, 0.f, 0.f, 0.f);
                if (!AF32) wbv = *(const float4*)(wb + c0);
                ushort4 s;
                s.x = f2b((acc[ct][rt][0] + wbv.x) * dv);
                s.y = f2b((acc[ct][rt][1] + wbv.y) * dv);
                s.z = f2b((acc[ct][rt][2] + wbv.z) * dv);
                s.w = f2b((acc[ct][rt][3] + wbv.w) * dv);
                *(ushort4*)(Cb + (size_t)r * 128 + c0) = s;
            }
        }
    }
}

// ---------------- aggregation + bias + relu: one wave per node, bf16 rows ----------------
// hW rows pre-scaled by dinv -> edge loop is pure {uniform csr load + row gather}.
__global__ __launch_bounds__(256) void agg_relu_b16(const unsigned int* __restrict__ hW32,
                                                    const int* __restrict__ rowp,
                                                    const int* __restrict__ cnt,
                                                    const int* __restrict__ csr,
                                                    const float* __restrict__ dinv,
                                                    const float* __restrict__ bias,
                                                    unsigned int* __restrict__ z32, int N) {
    int wave = threadIdx.x >> 6, lane = threadIdx.x & 63;
    int v = blockIdx.x * 4 + wave;
    if (v >= N) return;
    int beg = rowp[v];
    int num = cnt[v];
    float s0 = 0.f, s1 = 0.f;
    int i = 0;
    for (; i + 4 <= num; i += 4) {
        int u0 = csr[beg + i + 0];
        int u1 = csr[beg + i + 1];
        int u2 = csr[beg + i + 2];
        int u3 = csr[beg + i + 3];
        unsigned int p0 = hW32[(size_t)u0 * 64 + lane];
        unsigned int p1 = hW32[(size_t)u1 * 64 + lane];
        unsigned int p2 = hW32[(size_t)u2 * 64 + lane];
        unsigned int p3 = hW32[(size_t)u3 * 64 + lane];
        s0 += b2f_lo(p0) + b2f_lo(p1) + b2f_lo(p2) + b2f_lo(p3);
        s1 += b2f_hi(p0) + b2f_hi(p1) + b2f_hi(p2) + b2f_hi(p3);
    }
    for (; i < num; ++i) {
        int u = csr[beg + i];
        unsigned int p = hW32[(size_t)u * 64 + lane];
        s0 += b2f_lo(p);
        s1 += b2f_hi(p);
    }
    float dv = dinv[v];
    unsigned int pv = hW32[(size_t)v * 64 + lane];
    float r0 = dv * (s0 + b2f_lo(pv)) + bias[2 * lane];
    float r1 = dv * (s1 + b2f_hi(pv)) + bias[2 * lane + 1];
    unsigned int po = (unsigned int)f2b(fmaxf(r0, 0.f)) | ((unsigned int)f2b(fmaxf(r1, 0.f)) << 16);
    z32[(size_t)v * 64 + lane] = po;
}

// ---------------- BN statistics (bf16 input, row-major) ----------------
__global__ __launch_bounds__(256) void bn_stats_b16(const unsigned int* __restrict__ z32,
                                                    float* __restrict__ stats, int N) {
    int lane = threadIdx.x & 63, sub = threadIdx.x >> 6;
    float s0 = 0.f, s1 = 0.f, q0 = 0.f, q1 = 0.f;
    for (int v = blockIdx.x * 4 + sub; v < N; v += gridDim.x * 4) {
        unsigned int p = z32[(size_t)v * 64 + lane];
        float a = b2f_lo(p), c = b2f_hi(p);
        s0 += a; q0 = fmaf(a, a, q0);
        s1 += c; q1 = fmaf(c, c, q1);
    }
    __shared__ float ls[256][4];
    ls[threadIdx.x][0] = s0; ls[threadIdx.x][1] = s1;
    ls[threadIdx.x][2] = q0; ls[threadIdx.x][3] = q1;
    __syncthreads();
    if (sub == 0) {
        for (int k = 1; k < 4; ++k) {
            s0 += ls[lane + 64 * k][0]; s1 += ls[lane + 64 * k][1];
            q0 += ls[lane + 64 * k][2]; q1 += ls[lane + 64 * k][3];
        }
        atomicAdd(&stats[2 * lane], s0);
        atomicAdd(&stats[2 * lane + 1], s1);
        atomicAdd(&stats[128 + 2 * lane], q0);
        atomicAdd(&stats[129 + 2 * lane], q1);
    }
}

// ---------------- BN finalize + wb = sh @ Wnext for the next GEMM ----------------
__global__ void bn_finalize_wb(const float* __restrict__ stats, const float* __restrict__ g,
                               const float* __restrict__ be, float* __restrict__ ss,
                               const float* __restrict__ Wnext, float* __restrict__ wb,
                               float invN) {
    __shared__ float shv[128];
    int d = threadIdx.x;  // 128 threads
    float mu = stats[d] * invN;
    float var = stats[128 + d] * invN - mu * mu;
    float sc = g[d] * rsqrtf(var + BN_EPS);
    float sh = be[d] - mu * sc;
    ss[d] = sc;
    ss[128 + d] = sh;
    shv[d] = sh;
    __syncthreads();
    if (Wnext) {
        float acc = 0.f;
#pragma unroll 4
        for (int k = 0; k < 128; ++k) acc = fmaf(shv[k], Wnext[k * 128 + d], acc);
        wb[d] = acc;
    }
}

// ---------------- apply BN + pooled segment sum (read-only on z32) ----------------
__global__ __launch_bounds__(64) void apply_pool_b16(const unsigned int* __restrict__ z32,
                                                     const float* __restrict__ ss,
                                                     const int* __restrict__ batch,
                                                     float* __restrict__ out,
                                                     int layer, int N) {
    __shared__ int gb[32];
    int lane = threadIdx.x;
    int v0 = blockIdx.x * 32;
    int vend = min(v0 + 32, N);
    int cntv = vend - v0;
    if (lane < cntv) gb[lane] = batch[v0 + lane];
    __syncthreads();
    float sc0 = ss[2 * lane], sc1 = ss[2 * lane + 1];
    float sh0 = ss[128 + 2 * lane], sh1 = ss[129 + 2 * lane];
    float a0 = 0.f, a1 = 0.f;
    int cur = gb[0];
    for (int j = 0; j < cntv; ++j) {
        unsigned int p = z32[(size_t)(v0 + j) * 64 + lane];
        float x0 = fmaf(b2f_lo(p), sc0, sh0);
        float x1 = fmaf(b2f_hi(p), sc1, sh1);
        int g = gb[j];
        if (g != cur) {
            atomicAdd(&out[(size_t)cur * 384 + layer * 128 + 2 * lane], a0);
            atomicAdd(&out[(size_t)cur * 384 + layer * 128 + 2 * lane + 1], a1);
            a0 = a1 = 0.f;
            cur = g;
        }
        a0 += x0; a1 += x1;
    }
    atomicAdd(&out[(size_t)cur * 384 + layer * 128 + 2 * lane], a0);
    atomicAdd(&out[(size_t)cur * 384 + layer * 128 + 2 * lane + 1], a1);
}

// ---------------- launch ----------------
extern "C" void kernel_launch(void* const* d_in, const int* in_sizes, int n_in,
                              void* d_out, int out_size, void* d_ws, size_t ws_size,
                              hipStream_t stream) {
    const float* x    = (const float*)d_in[0];
    const int* eidx   = (const int*)d_in[1];
    const int* batch  = (const int*)d_in[2];

    const int N = in_sizes[2];          // 50000
    const int E = in_sizes[1] / 2;      // 1600000
    const int* src = eidx;
    const int* dst = eidx + E;

    const int nchunks = (E + CHUNK - 1) / CHUNK;   // 196
    const int NB = (N + 127) / 128;                // 391

    size_t off = 0;
    auto alloc = [&](size_t bytes) {
        void* p = (char*)d_ws + off;
        off += (bytes + 255) & ~(size_t)255;
        return p;
    };
    unsigned short* hWb = (unsigned short*)alloc((size_t)N * 128 * 2);  // bf16 dinv*h@W
    unsigned int* z32   = (unsigned int*)alloc((size_t)N * 64 * 4);     // bf16 post-agg
    unsigned int* bpairs= (unsigned int*)alloc((size_t)nchunks * CHUNK * 4);
    int*   csr   = (int*)alloc((size_t)E * 4);
    int*   cnts  = (int*)alloc((size_t)nchunks * NBU * 4);
    int*   cbase = (int*)alloc((size_t)nchunks * NBU * 4);
    int*   bbase = (int*)alloc((size_t)(NBU + 1) * 4);
    int*   btot  = (int*)alloc((size_t)NBU * 4);
    int*   degar = (int*)alloc((size_t)N * 4);
    int*   rowp  = (int*)alloc((size_t)N * 4);
    float* dinv  = (float*)alloc((size_t)N * 4);
    float* stats = (float*)alloc(3 * 256 * 4);
    float* ss    = (float*)alloc(3 * 256 * 4);
    float* wbuf  = (float*)alloc(2 * 128 * 4);
    unsigned short* Wp = (unsigned short*)alloc(128 * 128 * 2);

    float* out = (float*)d_out;

    hipMemsetAsync(stats, 0, 3 * 256 * 4, stream);
    hipMemsetAsync(btot, 0, (size_t)NBU * 4, stream);
    hipMemsetAsync(out, 0, (size_t)N_GRAPHS * 384 * 4, stream);

    bin_chunks<<<nchunks, 512, 0, stream>>>(src, dst, bpairs, cnts, cbase, btot, E);
    bucket_scan<<<1, 512, 0, stream>>>(btot, bbase);
    bucket_csr<<<NB, 256, 0, stream>>>(bpairs, cnts, cbase, bbase, rowp, degar, dinv, csr,
                                       nchunks, N);

    const int gemm_blocks = (N + 127) / 128;   // 391
    const int agg_blocks  = (N + 3) / 4;       // 12500
    const int pool_blocks = (N + 31) / 32;     // 1563

    for (int l = 0; l < 3; ++l) {
        const float* W  = (const float*)d_in[3 + 4 * l];
        const float* b  = (const float*)d_in[4 + 4 * l];
        const float* g  = (const float*)d_in[5 + 4 * l];
        const float* be = (const float*)d_in[6 + 4 * l];

        prep_w<<<64, 256, 0, stream>>>(W, (l == 0) ? (const float*)nullptr : ss + (l - 1) * 256, Wp);

        if (l == 0)
            gemm_mfma<1><<<gemm_blocks, 256, 0, stream>>>((const void*)x, Wp, nullptr, dinv, hWb, N);
        else
            gemm_mfma<0><<<gemm_blocks, 256, 0, stream>>>((const void*)z32, Wp,
                                                          wbuf + (l - 1) * 128, dinv, hWb, N);

        agg_relu_b16<<<agg_blocks, 256, 0, stream>>>((const unsigned int*)hWb, rowp, degar, csr,
                                                     dinv, b, z32, N);
        bn_stats_b16<<<256, 256, 0, stream>>>(z32, stats + l * 256, N);
        bn_finalize_wb<<<1, 128, 0, stream>>>(stats + l * 256, g, be, ss + l * 256,
                                              (l < 2) ? (const float*)d_in[3 + 4 * (l + 1)]
                                                      : (const float*)nullptr,
                                              wbuf + l * 128, 1.0f / N);
        apply_pool_b16<<<pool_blocks, 64, 0, stream>>>(z32, ss + l * 256, batch, out, l, N);
    }
}